// Round 1
// baseline (589.632 us; speedup 1.0000x reference)
//
#include <hip/hip_runtime.h>

// Problem constants (from reference)
#define K_BINS 64
#define N_SPLINE 191            // 3*64 - 1
constexpr float MIN_BIN_WIDTH  = 0.001f;
constexpr float MIN_BIN_HEIGHT = 0.001f;
constexpr float MIN_DERIV      = 0.001f;
constexpr float WINDOW_A = -10000.0f;
constexpr float AB       = 20000.0f;
constexpr float LOG_HALF = -0.69314718055994530942f;
constexpr float LOG_AB   = 9.90348755253612804622f;   // ln(20000)

// One wave (64 lanes) per cut; lane k owns bin k.
__global__ __launch_bounds__(256) void rqs_logdet_kernel(
    const float* __restrict__ value,
    const float* __restrict__ delta_spline,
    const int*   __restrict__ genes_oi,
    const int*   __restrict__ local_gene_ix,
    const float* __restrict__ spline_weight,
    float*       __restrict__ out,
    int n_cuts)
{
    const int lane = threadIdx.x & 63;
    const int wave = threadIdx.x >> 6;
    const int i = blockIdx.x * (blockDim.x >> 6) + wave;
    if (i >= n_cuts) return;

    const int g = genes_oi[local_gene_ix[i]];
    const float* __restrict__ sw = spline_weight + (long)g * N_SPLINE;
    const float* __restrict__ ds = delta_spline  + (long)i * N_SPLINE;

    // Coalesced row loads: lane k reads uw[k], uh[k], and ud element (k-1)
    // (address 127+k so all 64 lanes issue one contiguous 256B request).
    const float uw  = sw[lane]       + ds[lane];
    const float uh  = sw[64 + lane]  + ds[64 + lane];
    const float udv = sw[127 + lane] + ds[127 + lane];   // lane 0's value unused

    // ---- softmax (no max-subtract: inputs ~0.54 +/- 0.3, exp is safe) ----
    const float ew = __expf(uw);
    const float eh = __expf(uh);
    float sum_w = ew, sum_h = eh;
    #pragma unroll
    for (int m = 1; m < 64; m <<= 1) {
        sum_w += __shfl_xor(sum_w, m, 64);
        sum_h += __shfl_xor(sum_h, m, 64);
    }
    const float wk = fmaf(ew, __fdividef(1.0f - MIN_BIN_WIDTH  * K_BINS, sum_w), MIN_BIN_WIDTH);
    const float hk = fmaf(eh, __fdividef(1.0f - MIN_BIN_HEIGHT * K_BINS, sum_h), MIN_BIN_HEIGHT);

    // ---- inclusive prefix scans (6-step shfl_up) ----
    float pw = wk, ph = hk;
    #pragma unroll
    for (int off = 1; off < 64; off <<= 1) {
        const float tw = __shfl_up(pw, off, 64);
        const float th = __shfl_up(ph, off, 64);
        if (lane >= off) { pw += tw; ph += th; }
    }

    // ---- knots: cw/ch in [-1,1], endpoints forced exactly ----
    const float cw_r = (lane == 63) ?  1.0f : fmaf(2.0f, pw, -1.0f);
    const float cw_l = fmaf(2.0f, pw - wk, -1.0f);     // lane 0: pw-wk == 0 -> exactly -1
    const float ch_r = (lane == 63) ?  1.0f : fmaf(2.0f, ph, -1.0f);
    const float ch_l = fmaf(2.0f, ph - hk, -1.0f);
    const float wbin = cw_r - cw_l;
    const float hbin = ch_r - ch_l;

    // ---- x ----
    const float v = value[i];
    float x = fmaf(v - WINDOW_A, 2.0f / AB, -1.0f);
    const bool inside = (x >= -1.0f) && (x <= 1.0f);
    x = fminf(fmaxf(x, -1.0f), 1.0f);

    // ---- bin index: idx = #{k : x >= ch_right[k]} (lane 63's bin edge is
    // 1+1e-6 in the reference, i.e. never satisfied since x<=1 -> mask bit 63)
    const unsigned long long ball = __ballot(x >= ch_r) & 0x7FFFFFFFFFFFFFFFull;
    const int idx = __popcll(ball);

    // ---- derivatives: d[k] = MIN_DERIV + softplus(ud_padded[k]);
    // softplus(DEFAULT_INIT) = 1 - MIN_DERIV exactly -> boundary d = 1.0
    const float dval = (lane == 0) ? 1.0f
                     : (MIN_DERIV + __logf(1.0f + __expf(udv)));

    // ---- gather bin-idx quantities (idx is wave-uniform) ----
    const float in_cw = __shfl(cw_l, idx, 64);  (void)in_cw;
    const float in_w  = __shfl(wbin, idx, 64);  (void)in_w;
    const float in_ch = __shfl(ch_l, idx, 64);
    const float in_h  = __shfl(hbin, idx, 64);
    const float d0    = __shfl(dval, idx, 64);
    const float d1    = (idx == 63) ? 1.0f : __shfl(dval, idx + 1, 64);

    // ---- rational-quadratic inverse, logabsdet only ----
    const float delta = __fdividef(in_h, in_w);
    const float dy = x - in_ch;
    const float s2 = d0 + d1 - 2.0f * delta;
    const float aa = dy * s2 + in_h * (delta - d0);
    const float bb = in_h * d0 - dy * s2;
    const float cc = -delta * dy;
    const float disc = bb * bb - 4.0f * aa * cc;
    const float root = __fdividef(2.0f * cc, -bb - sqrtf(fmaxf(disc, 0.0f)));
    const float tom = root * (1.0f - root);
    const float denom = delta + s2 * tom;
    const float omr = 1.0f - root;
    const float dnum = delta * delta * (d1 * root * root + 2.0f * delta * tom + d0 * omr * omr);
    const float logabsdet = -(__logf(dnum) - 2.0f * __logf(denom));

    if (lane == 0)
        out[i] = LOG_HALF + (inside ? logabsdet : 0.0f) - LOG_AB;
}

extern "C" void kernel_launch(void* const* d_in, const int* in_sizes, int n_in,
                              void* d_out, int out_size, void* d_ws, size_t ws_size,
                              hipStream_t stream) {
    const float* value         = (const float*)d_in[0];
    const float* delta_spline  = (const float*)d_in[1];
    const int*   genes_oi      = (const int*)d_in[2];
    const int*   local_gene_ix = (const int*)d_in[3];
    const float* spline_weight = (const float*)d_in[4];
    float* out = (float*)d_out;

    const int n_cuts = in_sizes[0];
    const int waves_per_block = 4;              // 256 threads
    const int blocks = (n_cuts + waves_per_block - 1) / waves_per_block;
    rqs_logdet_kernel<<<blocks, 256, 0, stream>>>(
        value, delta_spline, genes_oi, local_gene_ix, spline_weight, out, n_cuts);
}

// Round 2
// 552.928 us; speedup vs baseline: 1.0664x; 1.0664x over previous
//
#include <hip/hip_runtime.h>

// Problem constants (from reference)
#define K_BINS 64
#define N_SPLINE 191            // 3*64 - 1
constexpr float MIN_BIN_WIDTH  = 0.001f;
constexpr float MIN_BIN_HEIGHT = 0.001f;
constexpr float MIN_DERIV      = 0.001f;
constexpr float WINDOW_A = -10000.0f;
constexpr float AB       = 20000.0f;
constexpr float LOG_HALF = -0.69314718055994530942f;
constexpr float LOG_AB   = 9.90348755253612804622f;   // ln(20000)

// ---- DPP helpers (no LDS, no lgkmcnt) ----
// update_dpp(old=0, src, ctrl, row_mask, bank_mask=0xf, bound_ctrl=1):
// masked/out-of-range lanes yield 0 == identity for add.
template<int CTRL, int ROW_MASK>
__device__ __forceinline__ float dpp_add(float x) {
    int t = __builtin_amdgcn_update_dpp(0, __float_as_int(x), CTRL, ROW_MASK, 0xf, true);
    return x + __int_as_float(t);
}

// Wave64 inclusive prefix sum (rocPRIM pattern):
// 4x row_shr within 16-lane rows, then row_bcast:15 (rows 1,3), row_bcast:31 (rows 2,3).
__device__ __forceinline__ float wave64_inclusive_scan(float x) {
    x = dpp_add<0x111, 0xf>(x);   // row_shr:1
    x = dpp_add<0x112, 0xf>(x);   // row_shr:2
    x = dpp_add<0x114, 0xf>(x);   // row_shr:4
    x = dpp_add<0x118, 0xf>(x);   // row_shr:8
    x = dpp_add<0x142, 0xa>(x);   // row_bcast:15 -> rows 1,3
    x = dpp_add<0x143, 0xc>(x);   // row_bcast:31 -> rows 2,3
    return x;
}

__device__ __forceinline__ float readlane_f(float x, int lane) {
    return __int_as_float(__builtin_amdgcn_readlane(__float_as_int(x), lane));
}

// One wave (64 lanes) per cut; lane k owns bin k. No LDS, no ds_bpermute.
__global__ __launch_bounds__(256) void rqs_logdet_kernel(
    const float* __restrict__ value,
    const float* __restrict__ delta_spline,
    const int*   __restrict__ genes_oi,
    const int*   __restrict__ local_gene_ix,
    const float* __restrict__ spline_weight,
    float*       __restrict__ out,
    int n_cuts)
{
    const int lane = threadIdx.x & 63;
    const int wave = threadIdx.x >> 6;
    const int i = blockIdx.x * (blockDim.x >> 6) + wave;
    if (i >= n_cuts) return;

    // i is wave-uniform -> these become scalar loads
    const int g = genes_oi[local_gene_ix[i]];
    const float v = value[i];

    const float* __restrict__ sw = spline_weight + (long)g * N_SPLINE;
    const float* __restrict__ ds = delta_spline  + (long)i * N_SPLINE;

    // Coalesced 256B row-segment loads: lane k reads uw[k], uh[k], ud[k-1]
    const float uw  = sw[lane]       + ds[lane];
    const float uh  = sw[64 + lane]  + ds[64 + lane];
    const float udv = sw[127 + lane] + ds[127 + lane];   // lane 0's value unused

    // exp (no max-subtract: inputs ~0.54 +/- 0.3, safe)
    const float ew = __expf(uw);
    const float eh = __expf(uh);

    // Single scan per array; softmax sum = scan[63] (fused reduce+scan).
    const float Ew = wave64_inclusive_scan(ew);
    const float Eh = wave64_inclusive_scan(eh);
    const float Sw = readlane_f(Ew, 63);
    const float Sh = readlane_f(Eh, 63);

    const float wsc = __fdividef(1.0f - MIN_BIN_WIDTH  * K_BINS, Sw);
    const float hsc = __fdividef(1.0f - MIN_BIN_HEIGHT * K_BINS, Sh);

    // w_k = MIN + wsc*e_k ; cumsum(w)_k = MIN*(k+1) + wsc*E_k  (affine in raw scan)
    const float wk = fmaf(ew, wsc, MIN_BIN_WIDTH);
    const float hk = fmaf(eh, hsc, MIN_BIN_HEIGHT);
    const float pw = fmaf(Ew, wsc, MIN_BIN_WIDTH  * (float)(lane + 1));
    const float ph = fmaf(Eh, hsc, MIN_BIN_HEIGHT * (float)(lane + 1));

    // knots in [-1,1], endpoints exact (lane0: pw-wk==0 exactly)
    const float cw_r = (lane == 63) ? 1.0f : fmaf(2.0f, pw, -1.0f);
    const float cw_l = fmaf(2.0f, pw - wk, -1.0f);
    const float ch_r = (lane == 63) ? 1.0f : fmaf(2.0f, ph, -1.0f);
    const float ch_l = fmaf(2.0f, ph - hk, -1.0f);
    const float wbin = cw_r - cw_l;
    const float hbin = ch_r - ch_l;

    // x
    float x = fmaf(v - WINDOW_A, 2.0f / AB, -1.0f);
    const bool inside = (x >= -1.0f) && (x <= 1.0f);
    x = fminf(fmaxf(x, -1.0f), 1.0f);

    // bin index: count of right-edges <= x over bins 0..62 (edge 63 is 1+1e-6, never hit)
    const unsigned long long ball = __ballot(x >= ch_r) & 0x7FFFFFFFFFFFFFFFull;
    const int idx = (int)__popcll(ball);   // wave-uniform -> SGPR

    // derivatives: d[k] = MIN + softplus(ud_padded[k]); boundary == 1.0 exactly
    const float dval = (lane == 0) ? 1.0f
                     : (MIN_DERIV + __logf(1.0f + __expf(udv)));

    // wave-uniform gathers via readlane (scalar, no LDS)
    const float in_w  = readlane_f(wbin, idx);
    const float in_ch = readlane_f(ch_l, idx);
    const float in_h  = readlane_f(hbin, idx);
    const float d0    = readlane_f(dval, idx);
    const float d1    = readlane_f(dval, (idx + 1) & 63);  // idx==63 -> dval[0]==1.0 == boundary

    // rational-quadratic inverse, logabsdet only
    const float delta = __fdividef(in_h, in_w);
    const float dy = x - in_ch;
    const float s2 = d0 + d1 - 2.0f * delta;
    const float aa = dy * s2 + in_h * (delta - d0);
    const float bb = in_h * d0 - dy * s2;
    const float cc = -delta * dy;
    const float disc = bb * bb - 4.0f * aa * cc;
    const float root = __fdividef(2.0f * cc, -bb - sqrtf(fmaxf(disc, 0.0f)));
    const float tom = root * (1.0f - root);
    const float denom = delta + s2 * tom;
    const float omr = 1.0f - root;
    const float dnum = delta * delta * (d1 * root * root + 2.0f * delta * tom + d0 * omr * omr);
    const float logabsdet = -(__logf(dnum) - 2.0f * __logf(denom));

    if (lane == 0)
        out[i] = LOG_HALF + (inside ? logabsdet : 0.0f) - LOG_AB;
}

extern "C" void kernel_launch(void* const* d_in, const int* in_sizes, int n_in,
                              void* d_out, int out_size, void* d_ws, size_t ws_size,
                              hipStream_t stream) {
    const float* value         = (const float*)d_in[0];
    const float* delta_spline  = (const float*)d_in[1];
    const int*   genes_oi      = (const int*)d_in[2];
    const int*   local_gene_ix = (const int*)d_in[3];
    const float* spline_weight = (const float*)d_in[4];
    float* out = (float*)d_out;

    const int n_cuts = in_sizes[0];
    const int waves_per_block = 4;              // 256 threads
    const int blocks = (n_cuts + waves_per_block - 1) / waves_per_block;
    rqs_logdet_kernel<<<blocks, 256, 0, stream>>>(
        value, delta_spline, genes_oi, local_gene_ix, spline_weight, out, n_cuts);
}